// Round 1
// baseline (478.973 us; speedup 1.0000x reference)
//
#include <hip/hip_runtime.h>

// ---- problem constants --------------------------------------------------
#define B_ 4
#define L_ 4096
#define D_ 256          // d_model
#define M_ 512          // num_features
#define C_ 256          // chunk length
#define NC_ 16          // chunks per batch (L_/C_)
#define NG_ (B_*NC_)    // total chunks = 64
#define EPS_ 1e-6f
#define RSQRT_D_ 0.0625f                 // 1/sqrt(256)
#define RSQRT_M_ 0.044194173824159216f   // 1/sqrt(512)

// ---- workspace layout (float offsets) -----------------------------------
#define OFF_QP  0
#define OFF_KP  (OFF_QP + B_*L_*M_)          // 8388608
#define OFF_S   (OFF_KP + B_*L_*M_)          // 16777216  (S -> exclusive prefix P, in place)
#define OFF_Z   (OFF_S  + NG_*M_*D_)         // 25165824  (z -> exclusive prefix, in place)
#define OFF_A   (OFF_Z  + NG_*M_)            // 25198592  (masked QK^T per chunk)
#define OFF_SQQ (OFF_A  + NG_*C_*C_)         // 29392896
#define OFF_SQK (OFF_SQQ + B_*L_)
#define OFF_DEN (OFF_SQK + B_*L_)
// total = 29442048 floats = ~118 MB

// ---- 0.5*||x||^2 per row (one wave per row) -----------------------------
__global__ __launch_bounds__(256) void rownorm_kernel(
    const float* __restrict__ q, const float* __restrict__ k,
    float* __restrict__ sqq, float* __restrict__ sqk) {
  int gid  = blockIdx.x * 256 + threadIdx.x;
  int wid  = gid >> 6;
  int lane = threadIdx.x & 63;
  const float* src; float* dst; int row;
  if (wid < B_*L_) { src = q; dst = sqq; row = wid; }
  else             { src = k; dst = sqk; row = wid - B_*L_; }
  float4 x = *(const float4*)&src[(size_t)row*D_ + lane*4];
  float s = x.x*x.x + x.y*x.y + x.z*x.z + x.w*x.w;
  #pragma unroll
  for (int off = 32; off > 0; off >>= 1) s += __shfl_down(s, off);
  if (lane == 0) dst[row] = 0.5f * s;
}

// ---- phi GEMM: out[row,m] = exp(X[row,:]@W[:,m]/16 - sq[row]) / sqrt(M) --
__global__ __launch_bounds__(256) void phi_kernel(
    const float* __restrict__ X, const float* __restrict__ W,
    const float* __restrict__ sqr, float* __restrict__ out) {
  __shared__ float As[16][68];   // [k][row]
  __shared__ float Bs[16][68];   // [k][col]
  const int tid = threadIdx.x;
  const int tx = tid & 15, ty = tid >> 4;
  const int row0 = blockIdx.y * 64, col0 = blockIdx.x * 64;
  float acc[4][4] = {};
  for (int k0 = 0; k0 < D_; k0 += 16) {
    #pragma unroll
    for (int j = 0; j < 4; ++j) {
      int li = tid + 256*j;
      As[li & 15][li >> 4] = X[(size_t)(row0 + (li >> 4))*D_ + k0 + (li & 15)];
      Bs[li >> 6][li & 63] = W[(size_t)(k0 + (li >> 6))*M_ + col0 + (li & 63)];
    }
    __syncthreads();
    #pragma unroll
    for (int kk = 0; kk < 16; ++kk) {
      float a[4], b[4];
      #pragma unroll
      for (int i = 0; i < 4; ++i) a[i] = As[kk][ty*4 + i];
      #pragma unroll
      for (int j = 0; j < 4; ++j) b[j] = Bs[kk][tx*4 + j];
      #pragma unroll
      for (int i = 0; i < 4; ++i)
        #pragma unroll
        for (int j = 0; j < 4; ++j)
          acc[i][j] = fmaf(a[i], b[j], acc[i][j]);
    }
    __syncthreads();
  }
  #pragma unroll
  for (int i = 0; i < 4; ++i) {
    int row = row0 + ty*4 + i;
    float sq = sqr[row];
    float4 o;
    o.x = __expf(fmaf(acc[i][0], RSQRT_D_, -sq)) * RSQRT_M_;
    o.y = __expf(fmaf(acc[i][1], RSQRT_D_, -sq)) * RSQRT_M_;
    o.z = __expf(fmaf(acc[i][2], RSQRT_D_, -sq)) * RSQRT_M_;
    o.w = __expf(fmaf(acc[i][3], RSQRT_D_, -sq)) * RSQRT_M_;
    *(float4*)&out[(size_t)row*M_ + col0 + tx*4] = o;
  }
}

// ---- per-chunk state S[g,m,d] = sum_t kp[t,m]*v[t,d] --------------------
__global__ __launch_bounds__(256) void chunkstate_kernel(
    const float* __restrict__ kp, const float* __restrict__ v,
    float* __restrict__ S) {
  __shared__ float Ks[16][68];   // [t][m]
  __shared__ float Vs[16][68];   // [t][d]
  const int tid = threadIdx.x;
  const int tx = tid & 15, ty = tid >> 4;
  const int g = blockIdx.z;
  const int m0 = blockIdx.y * 64, d0 = blockIdx.x * 64;
  const int cbase = g * C_;
  float acc[4][4] = {};
  for (int t0 = 0; t0 < C_; t0 += 16) {
    #pragma unroll
    for (int j = 0; j < 4; ++j) {
      int li = tid + 256*j;
      int tt = li >> 6, c = li & 63;
      Ks[tt][c] = kp[(size_t)(cbase + t0 + tt)*M_ + m0 + c];
      Vs[tt][c] = v [(size_t)(cbase + t0 + tt)*D_ + d0 + c];
    }
    __syncthreads();
    #pragma unroll
    for (int kk = 0; kk < 16; ++kk) {
      float a[4], b[4];
      #pragma unroll
      for (int i = 0; i < 4; ++i) a[i] = Ks[kk][ty*4 + i];
      #pragma unroll
      for (int j = 0; j < 4; ++j) b[j] = Vs[kk][tx*4 + j];
      #pragma unroll
      for (int i = 0; i < 4; ++i)
        #pragma unroll
        for (int j = 0; j < 4; ++j)
          acc[i][j] = fmaf(a[i], b[j], acc[i][j]);
    }
    __syncthreads();
  }
  #pragma unroll
  for (int i = 0; i < 4; ++i) {
    int m = m0 + ty*4 + i;
    float4 o = {acc[i][0], acc[i][1], acc[i][2], acc[i][3]};
    *(float4*)&S[(size_t)g*M_*D_ + (size_t)m*D_ + d0 + tx*4] = o;
  }
}

// ---- z[g,m] = sum_t kp[t,m] ---------------------------------------------
__global__ __launch_bounds__(256) void zsum_kernel(
    const float* __restrict__ kp, float* __restrict__ z) {
  int g = blockIdx.y;
  int m = blockIdx.x * 256 + threadIdx.x;
  const float* base = kp + (size_t)g*C_*M_ + m;
  float s = 0.f;
  for (int t = 0; t < C_; ++t) s += base[(size_t)t*M_];
  z[(size_t)g*M_ + m] = s;
}

// ---- in-place exclusive prefix over the NC_ chunks of each batch --------
// layout: [b][i][nper]; one thread per (b, e)
__global__ __launch_bounds__(256) void prefix_kernel(
    float* __restrict__ buf, int nper) {
  int j = blockIdx.x * 256 + threadIdx.x;
  int b = j / nper, e = j % nper;
  float run = 0.f;
  size_t idx = (size_t)(b*NC_)*nper + e;
  for (int i = 0; i < NC_; ++i) {
    float tmp = buf[idx];
    buf[idx] = run;
    run += tmp;
    idx += nper;
  }
}

// ---- A[g,t,t'] = (t'<=t) ? qp[t,:]*kp[t',:] : 0 -------------------------
__global__ __launch_bounds__(256) void qk_kernel(
    const float* __restrict__ qp, const float* __restrict__ kp,
    float* __restrict__ A) {
  const int g = blockIdx.z;
  const int tt0 = blockIdx.y * 64;   // rows (t)
  const int tp0 = blockIdx.x * 64;   // cols (t')
  const int tid = threadIdx.x;
  const int tx = tid & 15, ty = tid >> 4;
  float* Ag = A + (size_t)g*C_*C_;
  if (tp0 > tt0) {   // fully-masked tile
    #pragma unroll
    for (int i = 0; i < 4; ++i) {
      int t = tt0 + ty*4 + i;
      float4 zero = {0.f, 0.f, 0.f, 0.f};
      *(float4*)&Ag[(size_t)t*C_ + tp0 + tx*4] = zero;
    }
    return;
  }
  __shared__ float Qs[16][68];   // [m][t]
  __shared__ float Ks[16][68];   // [m][t']
  const int cbase = g * C_;
  float acc[4][4] = {};
  for (int m0 = 0; m0 < M_; m0 += 16) {
    #pragma unroll
    for (int j = 0; j < 4; ++j) {
      int li = tid + 256*j;
      int r = li >> 4, kk = li & 15;
      Qs[kk][r] = qp[(size_t)(cbase + tt0 + r)*M_ + m0 + kk];
      Ks[kk][r] = kp[(size_t)(cbase + tp0 + r)*M_ + m0 + kk];
    }
    __syncthreads();
    #pragma unroll
    for (int kk = 0; kk < 16; ++kk) {
      float a[4], b[4];
      #pragma unroll
      for (int i = 0; i < 4; ++i) a[i] = Qs[kk][ty*4 + i];
      #pragma unroll
      for (int j = 0; j < 4; ++j) b[j] = Ks[kk][tx*4 + j];
      #pragma unroll
      for (int i = 0; i < 4; ++i)
        #pragma unroll
        for (int j = 0; j < 4; ++j)
          acc[i][j] = fmaf(a[i], b[j], acc[i][j]);
    }
    __syncthreads();
  }
  #pragma unroll
  for (int i = 0; i < 4; ++i) {
    int t = tt0 + ty*4 + i;
    int tp = tp0 + tx*4;
    float4 o;
    o.x = (tp + 0 <= t) ? acc[i][0] : 0.f;
    o.y = (tp + 1 <= t) ? acc[i][1] : 0.f;
    o.z = (tp + 2 <= t) ? acc[i][2] : 0.f;
    o.w = (tp + 3 <= t) ? acc[i][3] : 0.f;
    *(float4*)&Ag[(size_t)t*C_ + tp] = o;
  }
}

// ---- den[row] = qp[row,:].zp[g,:] + sum_t' A[g,tloc,t'] + EPS -----------
__global__ __launch_bounds__(256) void den_kernel(
    const float* __restrict__ qp, const float* __restrict__ z,
    const float* __restrict__ A, float* __restrict__ den) {
  int gid  = blockIdx.x * 256 + threadIdx.x;
  int wid  = gid >> 6;           // global row
  int lane = threadIdx.x & 63;
  int g    = wid >> 8;
  int tloc = wid & 255;
  const float* qrow = qp + (size_t)wid*M_;
  const float* zp   = z  + (size_t)g*M_;
  const float* arow = A  + (size_t)g*C_*C_ + (size_t)tloc*C_;
  float s = 0.f;
  #pragma unroll
  for (int j = 0; j < 8; ++j) s = fmaf(qrow[lane + 64*j], zp[lane + 64*j], s);
  #pragma unroll
  for (int j = 0; j < 4; ++j) s += arow[lane + 64*j];
  #pragma unroll
  for (int off = 32; off > 0; off >>= 1) s += __shfl_down(s, off);
  if (lane == 0) den[wid] = s + EPS_;
}

// ---- out[t,d] = (qp[t,:]@P[g,:,d] + A[g,t,:]@v[:,d]) / den[t] -----------
__global__ __launch_bounds__(256) void out_kernel(
    const float* __restrict__ qp, const float* __restrict__ P,
    const float* __restrict__ A, const float* __restrict__ v,
    const float* __restrict__ den, float* __restrict__ out) {
  __shared__ float As[16][68];
  __shared__ float Bs[16][68];
  const int g = blockIdx.z;
  const int tt0 = blockIdx.y * 64, d0 = blockIdx.x * 64;
  const int tid = threadIdx.x;
  const int tx = tid & 15, ty = tid >> 4;
  const int cbase = g * C_;
  const float* Pg = P + (size_t)g*M_*D_;
  const float* Ag = A + (size_t)g*C_*C_;
  float acc[4][4] = {};
  // part 1: Q @ P  (K = M_)
  for (int m0 = 0; m0 < M_; m0 += 16) {
    #pragma unroll
    for (int j = 0; j < 4; ++j) {
      int li = tid + 256*j;
      As[li & 15][li >> 4] = qp[(size_t)(cbase + tt0 + (li >> 4))*M_ + m0 + (li & 15)];
      Bs[li >> 6][li & 63] = Pg[(size_t)(m0 + (li >> 6))*D_ + d0 + (li & 63)];
    }
    __syncthreads();
    #pragma unroll
    for (int kk = 0; kk < 16; ++kk) {
      float a[4], b[4];
      #pragma unroll
      for (int i = 0; i < 4; ++i) a[i] = As[kk][ty*4 + i];
      #pragma unroll
      for (int j = 0; j < 4; ++j) b[j] = Bs[kk][tx*4 + j];
      #pragma unroll
      for (int i = 0; i < 4; ++i)
        #pragma unroll
        for (int j = 0; j < 4; ++j)
          acc[i][j] = fmaf(a[i], b[j], acc[i][j]);
    }
    __syncthreads();
  }
  // part 2: A @ V  (K = C_)
  for (int tp0 = 0; tp0 < C_; tp0 += 16) {
    #pragma unroll
    for (int j = 0; j < 4; ++j) {
      int li = tid + 256*j;
      As[li & 15][li >> 4] = Ag[(size_t)(tt0 + (li >> 4))*C_ + tp0 + (li & 15)];
      Bs[li >> 6][li & 63] = v [(size_t)(cbase + tp0 + (li >> 6))*D_ + d0 + (li & 63)];
    }
    __syncthreads();
    #pragma unroll
    for (int kk = 0; kk < 16; ++kk) {
      float a[4], b[4];
      #pragma unroll
      for (int i = 0; i < 4; ++i) a[i] = As[kk][ty*4 + i];
      #pragma unroll
      for (int j = 0; j < 4; ++j) b[j] = Bs[kk][tx*4 + j];
      #pragma unroll
      for (int i = 0; i < 4; ++i)
        #pragma unroll
        for (int j = 0; j < 4; ++j)
          acc[i][j] = fmaf(a[i], b[j], acc[i][j]);
    }
    __syncthreads();
  }
  #pragma unroll
  for (int i = 0; i < 4; ++i) {
    int t = tt0 + ty*4 + i;
    int grow = cbase + t;
    float r = 1.0f / den[grow];   // den already includes EPS
    float4 o = {acc[i][0]*r, acc[i][1]*r, acc[i][2]*r, acc[i][3]*r};
    *(float4*)&out[(size_t)grow*D_ + d0 + tx*4] = o;
  }
}

// ---- host-side launch ---------------------------------------------------
extern "C" void kernel_launch(void* const* d_in, const int* in_sizes, int n_in,
                              void* d_out, int out_size, void* d_ws, size_t ws_size,
                              hipStream_t stream) {
  const float* q = (const float*)d_in[0];
  const float* k = (const float*)d_in[1];
  const float* v = (const float*)d_in[2];
  const float* W = (const float*)d_in[3];
  float* out = (float*)d_out;
  float* ws  = (float*)d_ws;

  float* qp  = ws + OFF_QP;
  float* kp  = ws + OFF_KP;
  float* S   = ws + OFF_S;
  float* z   = ws + OFF_Z;
  float* A   = ws + OFF_A;
  float* sqq = ws + OFF_SQQ;
  float* sqk = ws + OFF_SQK;
  float* den = ws + OFF_DEN;

  // 1. row norms for q and k
  rownorm_kernel<<<(2*B_*L_)/4, 256, 0, stream>>>(q, k, sqq, sqk);
  // 2. feature maps
  phi_kernel<<<dim3(M_/64, (B_*L_)/64), 256, 0, stream>>>(q, W, sqq, qp);
  phi_kernel<<<dim3(M_/64, (B_*L_)/64), 256, 0, stream>>>(k, W, sqk, kp);
  // 3. per-chunk KV state and key-sum
  chunkstate_kernel<<<dim3(D_/64, M_/64, NG_), 256, 0, stream>>>(kp, v, S);
  zsum_kernel<<<dim3(M_/256, NG_), 256, 0, stream>>>(kp, z);
  // 4. exclusive prefix over chunks (in place)
  prefix_kernel<<<(B_*M_*D_)/256, 256, 0, stream>>>(S, M_*D_);
  prefix_kernel<<<(B_*M_)/256,    256, 0, stream>>>(z, M_);
  // 5. masked intra-chunk QK^T
  qk_kernel<<<dim3(C_/64, C_/64, NG_), 256, 0, stream>>>(qp, kp, A);
  // 6. denominators
  den_kernel<<<(B_*L_)/4, 256, 0, stream>>>(qp, z, A, den);
  // 7. numerator GEMMs + divide
  out_kernel<<<dim3(D_/64, C_/64, NG_), 256, 0, stream>>>(qp, S, A, v, den, out);
}

// Round 2
// 206.872 us; speedup vs baseline: 2.3153x; 2.3153x over previous
//
#include <hip/hip_runtime.h>

// ---- problem constants --------------------------------------------------
#define B_ 4
#define L_ 4096
#define D_ 256
#define M_ 512
#define C_ 256
#define NC_ 16
#define NG_ (B_*NC_)
#define EPS_ 1e-6f
#define RSQRT_D_ 0.0625f
#define RSQRT_M_ 0.044194173824159216f

typedef __attribute__((ext_vector_type(8))) short short8;
typedef __attribute__((ext_vector_type(4))) short short4v;
typedef __attribute__((ext_vector_type(4))) float floatx4;

// ---- bf16 helpers (RNE) -------------------------------------------------
__device__ __forceinline__ short f2b(float f) {
  union { float f; unsigned u; } c; c.f = f;
  unsigned r = c.u + 0x7fffu + ((c.u >> 16) & 1u);
  return (short)(r >> 16);
}
__device__ __forceinline__ float b2f(short s) {
  union { unsigned u; float f; } c; c.u = ((unsigned)(unsigned short)s) << 16;
  return c.f;
}

// ---- workspace layout (byte offsets) ------------------------------------
// S_t fp32 [64][256 d][512 m]; Wt aliased over S head (dead before chunkstate)
#define OFF_S    0u
#define OFF_WT   0u
#define OFF_QP   33554432u          // bf16 [16384][512]
#define OFF_KP   50331648u          // bf16 [16384][512]
#define OFF_KPT  67108864u          // bf16 [64][512][256]
#define OFF_VT   83886080u          // bf16 [64][256][256]
#define OFF_AM   92274688u          // bf16 [64][256][256]
#define OFF_PB   100663296u         // bf16 [64][256][512]  (aliases qb/kb)
#define OFF_QB   100663296u         // bf16 [16384][256]
#define OFF_KB   109051904u         // bf16 [16384][256]
#define OFF_Z    117440512u         // fp32 [64][512]
#define OFF_SQQ  117571584u         // fp32 [16384]
#define OFF_SQK  117637120u         // fp32 [16384]
#define OFF_DEN  117571584u         // fp32 [16384] (aliases sqq, dead by then)
// total 117,702,656 B  (<= round-0 footprint)

// ======================================================================
// Shared MFMA GEMM core: C[128x128] += A[128xK] * B[128xK]^T
// A, B row-major [row][k]. 256 threads = 4 waves in 2x2. BK=64.
// Fragment-contiguous LDS layout with XOR swizzle -> conflict-free b128.
// ======================================================================
__device__ __forceinline__ void mfma_tile_gemm(
    const short* __restrict__ Ag, int lda,
    const short* __restrict__ Bg, int ldb,
    int K, short* sA, short* sB, floatx4 acc[4][4])
{
  const int tid  = threadIdx.x;
  const int lane = tid & 63;
  const int wave = tid >> 6;
  const int wm = wave >> 1, wn = wave & 1;
  const int q = lane >> 4, ml = lane & 15;

  for (int k0 = 0; k0 < K; k0 += 64) {
    #pragma unroll
    for (int it = 0; it < 4; ++it) {
      int ci = tid + 256 * it;          // 0..1023
      int m  = ci >> 3;                 // 0..127
      int k8 = ci & 7;                  // 16B chunk within 64-k
      short8 va = *(const short8*)(Ag + (size_t)m * lda + k0 + k8 * 8);
      short8 vb = *(const short8*)(Bg + (size_t)m * ldb + k0 + k8 * 8);
      int dst = (k8 >> 2) * 512 + (m >> 4) * 64 + (k8 & 3) * 16 + ((m & 15) ^ k8);
      *(short8*)(sA + dst * 8) = va;
      *(short8*)(sB + dst * 8) = vb;
    }
    __syncthreads();
    #pragma unroll
    for (int ks = 0; ks < 2; ++ks) {
      short8 a[4], b[4];
      int k8 = ks * 4 + q;
      #pragma unroll
      for (int i = 0; i < 4; ++i) {
        int ca = ks * 512 + (wm * 4 + i) * 64 + q * 16 + (ml ^ k8);
        a[i] = *(const short8*)(sA + ca * 8);
        int cb = ks * 512 + (wn * 4 + i) * 64 + q * 16 + (ml ^ k8);
        b[i] = *(const short8*)(sB + cb * 8);
      }
      #pragma unroll
      for (int i = 0; i < 4; ++i)
        #pragma unroll
        for (int j = 0; j < 4; ++j)
          acc[i][j] = __builtin_amdgcn_mfma_f32_16x16x32_bf16(a[i], b[j], acc[i][j], 0, 0, 0);
    }
    __syncthreads();
  }
}

// ---- K1: fp32 -> bf16 for q,k + 0.5*||x||^2 -----------------------------
__global__ __launch_bounds__(256) void cvt_qk_kernel(
    const float* __restrict__ q, const float* __restrict__ k,
    short* __restrict__ qb, short* __restrict__ kb,
    float* __restrict__ sqq, float* __restrict__ sqk)
{
  int wid  = blockIdx.x * 4 + (threadIdx.x >> 6);
  int lane = threadIdx.x & 63;
  const float* src; short* dstb; float* dsts; int row;
  if (wid < B_*L_) { src = q; dstb = qb; dsts = sqq; row = wid; }
  else             { src = k; dstb = kb; dsts = sqk; row = wid - B_*L_; }
  float4 x = *(const float4*)(src + (size_t)row * D_ + lane * 4);
  short4v b; b.x = f2b(x.x); b.y = f2b(x.y); b.z = f2b(x.z); b.w = f2b(x.w);
  *(short4v*)(dstb + (size_t)row * D_ + lane * 4) = b;
  float s = x.x*x.x + x.y*x.y + x.z*x.z + x.w*x.w;
  #pragma unroll
  for (int off = 32; off > 0; off >>= 1) s += __shfl_down(s, off);
  if (lane == 0) dsts[row] = 0.5f * s;
}

// ---- K2: W[k][n] fp32 -> Wt[n][k] bf16 (tiny, L2-resident) --------------
__global__ __launch_bounds__(256) void cvt_w_kernel(
    const float* __restrict__ W, short* __restrict__ Wt)
{
  int ci = blockIdx.x * 256 + threadIdx.x;   // 0..16383
  int n = ci >> 5, k8 = ci & 31;
  short8 o;
  #pragma unroll
  for (int u = 0; u < 8; ++u) o[u] = f2b(W[(size_t)(k8 * 8 + u) * M_ + n]);
  *(short8*)(Wt + (size_t)n * D_ + k8 * 8) = o;
}

// ---- K3: v fp32 [t][d] -> vT bf16 [g][d][t] (64x64 LDS transpose) -------
__global__ __launch_bounds__(256) void cvt_v_kernel(
    const float* __restrict__ v, short* __restrict__ vT)
{
  __shared__ short sm[64 * 65];
  const int g = blockIdx.z, t0 = blockIdx.y * 64, d0 = blockIdx.x * 64;
  const size_t vbase = ((size_t)g * C_ + t0) * D_ + d0;
  const int tid = threadIdx.x;
  #pragma unroll
  for (int it = 0; it < 4; ++it) {
    int ci = tid + 256 * it;      // 1024 float4 chunks
    int row = ci >> 4, c4 = ci & 15;
    float4 x = *(const float4*)(v + vbase + (size_t)row * D_ + c4 * 4);
    sm[(c4 * 4 + 0) * 65 + row] = f2b(x.x);
    sm[(c4 * 4 + 1) * 65 + row] = f2b(x.y);
    sm[(c4 * 4 + 2) * 65 + row] = f2b(x.z);
    sm[(c4 * 4 + 3) * 65 + row] = f2b(x.w);
  }
  __syncthreads();
  #pragma unroll
  for (int it = 0; it < 2; ++it) {
    int ci = tid + 256 * it;      // 512 out chunks
    int dr = ci >> 3, t8 = ci & 7;
    short8 o;
    #pragma unroll
    for (int u = 0; u < 8; ++u) o[u] = sm[dr * 65 + t8 * 8 + u];
    *(short8*)(vT + (size_t)g * (D_*C_) + (size_t)(d0 + dr) * C_ + t0 + t8 * 8) = o;
  }
}

// ---- K4/K5: phi = exp(X@W/sqrt(d) - sq)/sqrt(M), bf16 out ---------------
template<bool WRITE_T>
__global__ __launch_bounds__(256) void phi_mfma_kernel(
    const short* __restrict__ Xb, const short* __restrict__ Wt,
    const float* __restrict__ sqr,
    short* __restrict__ outP, short* __restrict__ outT)
{
  __shared__ short smem[17408];     // staging 2x8192; epilogue [128][136]
  short* sA = smem; short* sB = smem + 8192;
  const int row0 = blockIdx.y * 128, col0 = blockIdx.x * 128;
  floatx4 acc[4][4];
  #pragma unroll
  for (int i = 0; i < 4; ++i)
    #pragma unroll
    for (int j = 0; j < 4; ++j) acc[i][j] = (floatx4){0.f,0.f,0.f,0.f};

  mfma_tile_gemm(Xb + (size_t)row0 * D_, D_, Wt + (size_t)col0 * D_, D_, D_, sA, sB, acc);

  const int tid = threadIdx.x, lane = tid & 63, wave = tid >> 6;
  const int wm = wave >> 1, wn = wave & 1, q = lane >> 4, ln = lane & 15;
  #pragma unroll
  for (int i = 0; i < 4; ++i) {
    int rl = wm * 64 + i * 16 + q * 4;
    float sqv[4];
    #pragma unroll
    for (int r = 0; r < 4; ++r) sqv[r] = sqr[row0 + rl + r];
    #pragma unroll
    for (int j = 0; j < 4; ++j) {
      int cl = wn * 64 + j * 16 + ln;
      short4v tb;
      #pragma unroll
      for (int r = 0; r < 4; ++r) {
        float pv = __expf(fmaf(acc[i][j][r], RSQRT_D_, -sqv[r])) * RSQRT_M_;
        short bv = f2b(pv);
        outP[(size_t)(row0 + rl + r) * M_ + col0 + cl] = bv;
        tb[r] = bv;
      }
      if (WRITE_T)  // col-major LDS [col][row+pad8] for transposed write
        *(short4v*)(smem + (size_t)cl * 136 + rl) = tb;
    }
  }
  if (WRITE_T) {
    __syncthreads();
    int g = row0 >> 8, tb0 = row0 & 255;
    #pragma unroll
    for (int it = 0; it < 8; ++it) {
      int ci = tid + 256 * it;      // 2048 chunks
      int t8 = ci & 15, cc = ci >> 4;
      short8 vv = *(const short8*)(smem + (size_t)cc * 136 + t8 * 8);
      *(short8*)(outT + (size_t)g * (M_*C_) + (size_t)(col0 + cc) * C_ + tb0 + t8 * 8) = vv;
    }
  }
}

// ---- K6: S_t[g][d][m] = sum_t vT[g][d][t]*kpT[g][m][t], fp32 out --------
__global__ __launch_bounds__(256) void chunkstate_mfma_kernel(
    const short* __restrict__ vT, const short* __restrict__ kpT,
    float* __restrict__ S)
{
  __shared__ short smem[16384];
  const int g = blockIdx.z, d0 = blockIdx.y * 128, m0 = blockIdx.x * 128;
  floatx4 acc[4][4];
  #pragma unroll
  for (int i = 0; i < 4; ++i)
    #pragma unroll
    for (int j = 0; j < 4; ++j) acc[i][j] = (floatx4){0.f,0.f,0.f,0.f};
  mfma_tile_gemm(vT + (size_t)g * (D_*C_) + (size_t)d0 * C_, C_,
                 kpT + (size_t)g * (M_*C_) + (size_t)m0 * C_, C_, C_,
                 smem, smem + 8192, acc);
  const int tid = threadIdx.x, lane = tid & 63, wave = tid >> 6;
  const int wm = wave >> 1, wn = wave & 1, q = lane >> 4, ln = lane & 15;
  #pragma unroll
  for (int i = 0; i < 4; ++i) {
    int rl = d0 + wm * 64 + i * 16 + q * 4;
    #pragma unroll
    for (int j = 0; j < 4; ++j) {
      int cl = m0 + wn * 64 + j * 16 + ln;
      #pragma unroll
      for (int r = 0; r < 4; ++r)
        S[((size_t)g * D_ + rl + r) * M_ + cl] = acc[i][j][r];
    }
  }
}

// ---- K7: z[g][m] = column sums of kp chunk ------------------------------
__global__ __launch_bounds__(256) void zsum_kernel(
    const short* __restrict__ kp, float* __restrict__ z)
{
  int g = blockIdx.y;
  int m = blockIdx.x * 256 + threadIdx.x;
  const short* base = kp + (size_t)g * C_ * M_ + m;
  float s = 0.f;
  for (int t = 0; t < C_; ++t) s += b2f(base[(size_t)t * M_]);
  z[(size_t)g * M_ + m] = s;
}

// ---- K8: exclusive chunk prefix of S (fp32 in) -> Pb (bf16 out) ---------
__global__ __launch_bounds__(256) void prefixS_kernel(
    const float* __restrict__ S, short* __restrict__ Pb)
{
  int j = blockIdx.x * 256 + threadIdx.x;   // 524288
  int b = j >> 17, e = j & 131071;
  float run = 0.f;
  size_t idx = ((size_t)b * NC_) * 131072 + e;
  for (int i = 0; i < NC_; ++i) {
    float t = S[idx];
    Pb[idx] = f2b(run);
    run += t;
    idx += 131072;
  }
}

// ---- K9: exclusive chunk prefix of z (fp32 in place) --------------------
__global__ __launch_bounds__(256) void prefixz_kernel(float* __restrict__ z)
{
  int j = blockIdx.x * 256 + threadIdx.x;   // 2048
  int b = j >> 9, m = j & 511;
  float run = 0.f;
  size_t idx = ((size_t)b * NC_) * M_ + m;
  for (int i = 0; i < NC_; ++i) {
    float t = z[idx];
    z[idx] = run;
    run += t;
    idx += M_;
  }
}

// ---- K10: Amat[g][t][t'] = masked qp.kp^T, bf16 out ---------------------
__global__ __launch_bounds__(256) void qk_mfma_kernel(
    const short* __restrict__ qp, const short* __restrict__ kp,
    short* __restrict__ Am)
{
  const int g = blockIdx.z;
  const int tt0 = blockIdx.y * 128, tp0 = blockIdx.x * 128;
  short* Ag = Am + (size_t)g * (C_*C_);
  const int tid = threadIdx.x;
  if (tp0 > tt0) {                  // fully masked tile -> zeros
    short8 z8 = 0;
    #pragma unroll
    for (int it = 0; it < 8; ++it) {
      int ci = tid + 256 * it;
      int row = ci >> 4, c8 = ci & 15;
      *(short8*)(Ag + (size_t)(tt0 + row) * C_ + tp0 + c8 * 8) = z8;
    }
    return;
  }
  __shared__ short smem[16384];
  floatx4 acc[4][4];
  #pragma unroll
  for (int i = 0; i < 4; ++i)
    #pragma unroll
    for (int j = 0; j < 4; ++j) acc[i][j] = (floatx4){0.f,0.f,0.f,0.f};
  const size_t cb = (size_t)g * C_;
  mfma_tile_gemm(qp + (cb + tt0) * M_, M_, kp + (cb + tp0) * M_, M_, M_,
                 smem, smem + 8192, acc);
  const int lane = tid & 63, wave = tid >> 6;
  const int wm = wave >> 1, wn = wave & 1, q = lane >> 4, ln = lane & 15;
  #pragma unroll
  for (int i = 0; i < 4; ++i) {
    int rl = tt0 + wm * 64 + i * 16 + q * 4;
    #pragma unroll
    for (int j = 0; j < 4; ++j) {
      int cl = tp0 + wn * 64 + j * 16 + ln;
      #pragma unroll
      for (int r = 0; r < 4; ++r) {
        short bv = (cl <= rl + r) ? f2b(acc[i][j][r]) : (short)0;
        Ag[(size_t)(rl + r) * C_ + cl] = bv;
      }
    }
  }
}

// ---- K11: den[row] = qp.z_prefix + rowsum(Amat) + eps -------------------
__global__ __launch_bounds__(256) void den_kernel(
    const short* __restrict__ qp, const float* __restrict__ z,
    const short* __restrict__ Am, float* __restrict__ den)
{
  int wid  = blockIdx.x * 4 + (threadIdx.x >> 6);
  int lane = threadIdx.x & 63;
  int g = wid >> 8, tl = wid & 255;
  short8 qv = *(const short8*)(qp + (size_t)wid * M_ + lane * 8);
  const float* zp = z + (size_t)g * M_ + lane * 8;
  float4 z1 = *(const float4*)(zp);
  float4 z2 = *(const float4*)(zp + 4);
  float s = 0.f;
  s = fmaf(b2f(qv[0]), z1.x, s); s = fmaf(b2f(qv[1]), z1.y, s);
  s = fmaf(b2f(qv[2]), z1.z, s); s = fmaf(b2f(qv[3]), z1.w, s);
  s = fmaf(b2f(qv[4]), z2.x, s); s = fmaf(b2f(qv[5]), z2.y, s);
  s = fmaf(b2f(qv[6]), z2.z, s); s = fmaf(b2f(qv[7]), z2.w, s);
  short4v av = *(const short4v*)(Am + (size_t)g * (C_*C_) + (size_t)tl * C_ + lane * 4);
  s += b2f(av.x) + b2f(av.y) + b2f(av.z) + b2f(av.w);
  #pragma unroll
  for (int off = 32; off > 0; off >>= 1) s += __shfl_down(s, off);
  if (lane == 0) den[wid] = s + EPS_;
}

// ---- K12: out = (qp@Pb^T + Amat@vT^T) / den -----------------------------
__global__ __launch_bounds__(256) void out_mfma_kernel(
    const short* __restrict__ qp, const short* __restrict__ Pb,
    const short* __restrict__ Am, const short* __restrict__ vT,
    const float* __restrict__ den, float* __restrict__ out)
{
  __shared__ short smem[16384];
  const int g = blockIdx.z;
  const int tt0 = blockIdx.y * 128, d0 = blockIdx.x * 128;
  floatx4 acc[4][4];
  #pragma unroll
  for (int i = 0; i < 4; ++i)
    #pragma unroll
    for (int j = 0; j < 4; ++j) acc[i][j] = (floatx4){0.f,0.f,0.f,0.f};
  mfma_tile_gemm(qp + ((size_t)g * C_ + tt0) * M_, M_,
                 Pb + (size_t)g * (D_*M_) + (size_t)d0 * M_, M_, M_,
                 smem, smem + 8192, acc);
  mfma_tile_gemm(Am + ((size_t)g * C_ + tt0) * C_, C_,
                 vT + (size_t)g * (D_*C_) + (size_t)d0 * C_, C_, C_,
                 smem, smem + 8192, acc);
  const int tid = threadIdx.x, lane = tid & 63, wave = tid >> 6;
  const int wm = wave >> 1, wn = wave & 1, q = lane >> 4, ln = lane & 15;
  #pragma unroll
  for (int i = 0; i < 4; ++i) {
    int rl = tt0 + wm * 64 + i * 16 + q * 4;
    #pragma unroll
    for (int r = 0; r < 4; ++r) {
      int grow = g * C_ + rl + r;
      float rc = 1.0f / den[grow];
      #pragma unroll
      for (int j = 0; j < 4; ++j) {
        int cl = d0 + wn * 64 + j * 16 + ln;
        out[(size_t)grow * D_ + cl] = acc[i][j][r] * rc;
      }
    }
  }
}

// ---- host-side launch ---------------------------------------------------
extern "C" void kernel_launch(void* const* d_in, const int* in_sizes, int n_in,
                              void* d_out, int out_size, void* d_ws, size_t ws_size,
                              hipStream_t stream) {
  const float* q = (const float*)d_in[0];
  const float* k = (const float*)d_in[1];
  const float* v = (const float*)d_in[2];
  const float* W = (const float*)d_in[3];
  float* out = (float*)d_out;
  char* ws = (char*)d_ws;

  float* S   = (float*)(ws + OFF_S);
  short* Wt  = (short*)(ws + OFF_WT);
  short* qp  = (short*)(ws + OFF_QP);
  short* kp  = (short*)(ws + OFF_KP);
  short* kpT = (short*)(ws + OFF_KPT);
  short* vT  = (short*)(ws + OFF_VT);
  short* Am  = (short*)(ws + OFF_AM);
  short* Pb  = (short*)(ws + OFF_PB);
  short* qb  = (short*)(ws + OFF_QB);
  short* kb  = (short*)(ws + OFF_KB);
  float* z   = (float*)(ws + OFF_Z);
  float* sqq = (float*)(ws + OFF_SQQ);
  float* sqk = (float*)(ws + OFF_SQK);
  float* den = (float*)(ws + OFF_DEN);

  cvt_qk_kernel<<<(2*B_*L_)/4, 256, 0, stream>>>(q, k, qb, kb, sqq, sqk);
  cvt_w_kernel<<<64, 256, 0, stream>>>(W, Wt);
  cvt_v_kernel<<<dim3(4, 4, NG_), 256, 0, stream>>>(v, vT);
  phi_mfma_kernel<false><<<dim3(M_/128, (B_*L_)/128), 256, 0, stream>>>(qb, Wt, sqq, qp, nullptr);
  phi_mfma_kernel<true ><<<dim3(M_/128, (B_*L_)/128), 256, 0, stream>>>(kb, Wt, sqk, kp, kpT);
  chunkstate_mfma_kernel<<<dim3(M_/128, D_/128, NG_), 256, 0, stream>>>(vT, kpT, S);
  zsum_kernel<<<dim3(M_/256, NG_), 256, 0, stream>>>(kp, z);
  prefixS_kernel<<<(B_*D_*M_)/256, 256, 0, stream>>>(S, Pb);
  prefixz_kernel<<<(B_*M_)/256, 256, 0, stream>>>(z);
  qk_mfma_kernel<<<dim3(C_/128, C_/128, NG_), 256, 0, stream>>>(qp, kp, Am);
  den_kernel<<<(B_*L_)/4, 256, 0, stream>>>(qp, z, Am, den);
  out_mfma_kernel<<<dim3(D_/128, C_/128, NG_), 256, 0, stream>>>(qp, Pb, Am, vT, den, out);
}